// Round 2
// baseline (514.050 us; speedup 1.0000x reference)
//
#include <hip/hip_runtime.h>

using u16 = unsigned short;
using u32 = unsigned int;
typedef float f32x4 __attribute__((ext_vector_type(4)));
typedef float f32x16 __attribute__((ext_vector_type(16)));
typedef short s16x8 __attribute__((ext_vector_type(8)));
typedef short s16x4 __attribute__((ext_vector_type(4)));
typedef unsigned int u32x4 __attribute__((ext_vector_type(4)));

// ---------- helpers ----------
__device__ __forceinline__ u16 f2bf(float x) {
  u32 u = __float_as_uint(x);
  u += 0x7fffu + ((u >> 16) & 1u);   // RTNE
  return (u16)(u >> 16);
}
__device__ __forceinline__ u32 pack2bf(float lo, float hi) {
  return (u32)f2bf(lo) | ((u32)f2bf(hi) << 16);
}
__device__ __forceinline__ float bf2f(u16 v) {
  return __uint_as_float(((u32)v) << 16);
}
__device__ __forceinline__ u32 cvtpk(float lo, float hi) {
  u32 r;
  asm("v_cvt_pk_bf16_f32 %0, %1, %2" : "=v"(r) : "v"(lo), "v"(hi));
  return r;
}
__device__ __forceinline__ void plswap(u32& a, u32& b) {
  // v_permlane32_swap_b32: a.lanes[32:63] <-> b.lanes[0:31]
  asm volatile("v_permlane32_swap_b32 %0, %1" : "+v"(a), "+v"(b));
}
__device__ __forceinline__ void gload16(const u16* g, u16* l) {
  __builtin_amdgcn_global_load_lds(
      (__attribute__((address_space(1))) void*)(u16*)g,
      (__attribute__((address_space(3))) void*)l, 16, 0, 0);
}
__device__ __forceinline__ f32x4 fzero4() {
  f32x4 v = {0.f, 0.f, 0.f, 0.f};
  return v;
}
__device__ __forceinline__ f32x16 fzero16() {
  f32x16 v = {0, 0, 0, 0, 0, 0, 0, 0, 0, 0, 0, 0, 0, 0, 0, 0};
  return v;
}

// ---------- fp32 -> bf16 convert (vectorized) ----------
__global__ __launch_bounds__(256) void k_convert(const float* __restrict__ in,
                                                 u16* __restrict__ out, int n8) {
  int i = blockIdx.x * 256 + threadIdx.x;
  if (i >= n8) return;
  const float4* p = (const float4*)in;
  float4 a = p[2 * i], b = p[2 * i + 1];
  uint4 o;
  o.x = pack2bf(a.x, a.y);
  o.y = pack2bf(a.z, a.w);
  o.z = pack2bf(b.x, b.y);
  o.w = pack2bf(b.z, b.w);
  ((uint4*)out)[i] = o;
}

// ---------- transpose + convert: w [K][N] f32 -> wt [N][K] bf16 ----------
__global__ __launch_bounds__(256) void k_transpose(const float* __restrict__ w,
                                                   u16* __restrict__ wt, int N, int K) {
  __shared__ float tile[64][65];
  int n0 = blockIdx.x * 64, k0 = blockIdx.y * 64;
  int tid = threadIdx.x;
  int rr = tid >> 6, cc = tid & 63;
#pragma unroll
  for (int p = 0; p < 16; ++p)
    tile[p * 4 + rr][cc] = w[(size_t)(k0 + p * 4 + rr) * N + n0 + cc];
  __syncthreads();
#pragma unroll
  for (int p = 0; p < 16; ++p)
    wt[(size_t)(n0 + p * 4 + rr) * K + k0 + cc] = f2bf(tile[cc][p * 4 + rr]);
}

// ---------- GEMM: C[M,N] = A[M,K](bf16) x Bt[N,K](bf16), out bf16 or fp32 ----------
template <bool OBF>
__global__ __launch_bounds__(256) void k_gemm_bt(const u16* __restrict__ A,
                                                 const u16* __restrict__ Bt,
                                                 void* __restrict__ Out, int Nd, int Kd) {
  __shared__ u16 As[2][128 * 32];
  __shared__ u16 Bs[2][128 * 32];
  u32 bid = blockIdx.x, nwg = gridDim.x;
  u32 wgid = (bid & 7) * (nwg >> 3) + (bid >> 3);   // XCD swizzle (nwg % 8 == 0)
  int ntn = Nd >> 7;
  int bm = wgid / ntn, bn = wgid % ntn;
  int tid = threadIdx.x, w = tid >> 6, lane = tid & 63;
  int wm = w >> 1, wn = w & 1;
  int lg = lane >> 4, lq = lane & 15;

  const u16* a0 = A + (size_t)(bm * 128 + w * 32 + (lane >> 2)) * Kd + (lane & 3) * 8;
  const u16* a1 = a0 + (size_t)16 * Kd;
  const u16* b0 = Bt + (size_t)(bn * 128 + w * 32 + (lane >> 2)) * Kd + (lane & 3) * 8;
  const u16* b1 = b0 + (size_t)16 * Kd;

  auto stage = [&](int buf, int k0) {
    gload16(a0 + k0, &As[buf][w * 1024]);
    gload16(a1 + k0, &As[buf][w * 1024 + 512]);
    gload16(b0 + k0, &Bs[buf][w * 1024]);
    gload16(b1 + k0, &Bs[buf][w * 1024 + 512]);
  };

  f32x4 acc[4][4];
#pragma unroll
  for (int m = 0; m < 4; ++m)
#pragma unroll
    for (int n = 0; n < 4; ++n) acc[m][n] = fzero4();

  int nk = Kd >> 5;
  stage(0, 0);
  __syncthreads();
  for (int t = 0; t < nk; ++t) {
    int cur = t & 1;
    if (t + 1 < nk) stage(cur ^ 1, (t + 1) << 5);
    s16x8 af[4], bfr[4];
#pragma unroll
    for (int m = 0; m < 4; ++m)
      af[m] = *(const s16x8*)&As[cur][(wm * 64 + m * 16 + lq) * 32 + lg * 8];
#pragma unroll
    for (int n = 0; n < 4; ++n)
      bfr[n] = *(const s16x8*)&Bs[cur][(wn * 64 + n * 16 + lq) * 32 + lg * 8];
#pragma unroll
    for (int m = 0; m < 4; ++m)
#pragma unroll
      for (int n = 0; n < 4; ++n)
        acc[m][n] = __builtin_amdgcn_mfma_f32_16x16x32_bf16(af[m], bfr[n], acc[m][n], 0, 0, 0);
    __syncthreads();
  }

  int r0 = bm * 128 + wm * 64, c0 = bn * 128 + wn * 64;
  if (OBF) {
    u16* O = (u16*)Out;
#pragma unroll
    for (int m = 0; m < 4; ++m)
#pragma unroll
      for (int n = 0; n < 4; ++n)
#pragma unroll
        for (int r = 0; r < 4; ++r)
          O[(size_t)(r0 + m * 16 + lg * 4 + r) * Nd + c0 + n * 16 + lq] = f2bf(acc[m][n][r]);
  } else {
    float* O = (float*)Out;
#pragma unroll
    for (int m = 0; m < 4; ++m)
#pragma unroll
      for (int n = 0; n < 4; ++n)
#pragma unroll
        for (int r = 0; r < 4; ++r)
          O[(size_t)(r0 + m * 16 + lg * 4 + r) * Nd + c0 + n * 16 + lq] = acc[m][n][r];
  }
}

// ---------- RoPE + scatter to Q / K / V^T (Q pre-scaled by 1/sqrt(HD)*log2e) ----------
__device__ __forceinline__ u32 rope_pair(short a, short b, float c, float s, float sc) {
  float x0 = bf2f((u16)a), x1 = bf2f((u16)b);
  return pack2bf((x0 * c - x1 * s) * sc, (x0 * s + x1 * c) * sc);
}

__global__ __launch_bounds__(256) void k_rope_scatter(const u16* __restrict__ qkv,
                                                      const float* __restrict__ fr,
                                                      u16* __restrict__ Q, u16* __restrict__ K,
                                                      u16* __restrict__ Vt) {
  int idx = blockIdx.x * 256 + threadIdx.x;
  if (idx >= 8192 * 384) return;
  int row = idx / 384, g = idx % 384;
  int b = row >> 11, t = row & 2047;
  int col = g * 8;
  const u16* src = qkv + (size_t)row * 3072 + col;
  if (col < 2560) {
    int isq = col < 2048;
    float sc = isq ? 0.127517432f : 1.0f;   // (1/sqrt(128))*log2(e) folded into Q
    int c2 = isq ? col : col - 2048;
    int h = c2 >> 7, d = c2 & 127;
    u16* dst = isq ? (Q + ((size_t)(b * 16 + h) * 2048 + t) * 128 + d)
                   : (K + ((size_t)(b * 4 + h) * 2048 + t) * 128 + d);
    const float4* fp = (const float4*)(fr + (size_t)t * 128 + d);
    float4 f01 = fp[0], f23 = fp[1];
    s16x8 v = *(const s16x8*)src;
    uint4 o;
    o.x = rope_pair(v[0], v[1], f01.x, f01.y, sc);
    o.y = rope_pair(v[2], v[3], f01.z, f01.w, sc);
    o.z = rope_pair(v[4], v[5], f23.x, f23.y, sc);
    o.w = rope_pair(v[6], v[7], f23.z, f23.w, sc);
    *(uint4*)dst = o;
  } else {
    int c2 = col - 2560;
    int h = c2 >> 7, d = c2 & 127;
    s16x8 v = *(const s16x8*)src;
    u16* base = Vt + ((size_t)(b * 4 + h) * 128 + d) * 2048 + t;
#pragma unroll
    for (int j = 0; j < 8; ++j) base[(size_t)j * 2048] = (u16)v[j];
  }
}

// ---------- flash attention, 32x32 MFMA, in-register P ----------
// Q [64bh][2048][128] (pre-scaled), K [16bkv][2048][128], Vt [16bkv][128][2048]
// -> Y [B*T][2048] bf16.  4 waves x 32q = 128 q-rows per block, KV tile 64.
__global__ __launch_bounds__(256) void k_attn(const u16* __restrict__ Qg,
                                              const u16* __restrict__ Kg,
                                              const u16* __restrict__ Vg,
                                              u16* __restrict__ Yg) {
  __shared__ u16 Kl[64 * 128];     // 16 KB, 4-bit XOR swizzle on 16B slots
  __shared__ u16 Vl[128 * 68];     // 17 KB, +4 u16 pad (34-bank row stride)
  u32 bid = blockIdx.x;
  u32 wgid = (bid & 7) * 128 + (bid >> 3);   // XCD swizzle (1024 wgs)
  int qt = wgid & 15, bh = wgid >> 4;
  int b = bh >> 4, h = bh & 15, kvh = h >> 2;
  int tid = threadIdx.x, w = tid >> 6, lane = tid & 63;
  int l31 = lane & 31, hi = lane >> 5;
  const u16* Qb = Qg + ((size_t)bh * 2048 + qt * 128 + w * 32 + l31) * 128;
  const u16* Kb = Kg + (size_t)(b * 4 + kvh) * 2048 * 128;
  const u16* Vb = Vg + (size_t)(b * 4 + kvh) * 128 * 2048;

  // Q fragments: B-operand of 32x32x16, col=q=l31, k = hi*8+j within kc*16
  s16x8 qf[8];
#pragma unroll
  for (int kc = 0; kc < 8; ++kc)
    qf[kc] = *(const s16x8*)(Qb + kc * 16 + hi * 8);

  f32x16 o[4];
#pragma unroll
  for (int i = 0; i < 4; ++i) o[i] = fzero16();
  float m_run = -3.0e38f, l_run = 0.f;

  // staging geometry
  int krow4 = lane >> 4;           // row-within-4 for K gload
  int kc_ = lane & 15;             // 16B slot within K row
  int vd = tid >> 3;               // V d-row (0..31), +32*i
  int vc = tid & 7;                // 16B slot within V row (8 per 64-key row)
  const u16* vsrc = Vb + (size_t)vd * 2048 + vc * 8;

  // prefetch V tile 0 into regs
  uint4 tv0 = *(const uint4*)(vsrc);
  uint4 tv1 = *(const uint4*)(vsrc + (size_t)32 * 2048);
  uint4 tv2 = *(const uint4*)(vsrc + (size_t)64 * 2048);
  uint4 tv3 = *(const uint4*)(vsrc + (size_t)96 * 2048);

  for (int kt = 0; kt < 32; ++kt) {
    int key0 = kt * 64;
    __syncthreads();   // prior iter's LDS reads done
    // K tile -> LDS direct (pre-swizzled source, linear dest)
#pragma unroll
    for (int i = 0; i < 4; ++i) {
      int key = w * 16 + i * 4 + krow4;
      gload16(Kb + (size_t)(key0 + key) * 128 + ((kc_ ^ (key & 15)) * 8),
              &Kl[(w * 4 + i) * 512]);
    }
    // V tile regs -> padded LDS (two b64 writes per row chunk)
    {
      u16* p = &Vl[vd * 68 + vc * 8];
      *(uint2*)p = make_uint2(tv0.x, tv0.y);
      *(uint2*)(p + 4) = make_uint2(tv0.z, tv0.w);
      p += 32 * 68;
      *(uint2*)p = make_uint2(tv1.x, tv1.y);
      *(uint2*)(p + 4) = make_uint2(tv1.z, tv1.w);
      p += 32 * 68;
      *(uint2*)p = make_uint2(tv2.x, tv2.y);
      *(uint2*)(p + 4) = make_uint2(tv2.z, tv2.w);
      p += 32 * 68;
      *(uint2*)p = make_uint2(tv3.x, tv3.y);
      *(uint2*)(p + 4) = make_uint2(tv3.z, tv3.w);
    }
    __syncthreads();   // barrier drains gload16 + ds_writes

    // prefetch next V tile during compute
    {
      int keyn = (kt < 31 ? key0 + 64 : key0);
      tv0 = *(const uint4*)(vsrc + keyn);
      tv1 = *(const uint4*)(vsrc + keyn + (size_t)32 * 2048);
      tv2 = *(const uint4*)(vsrc + keyn + (size_t)64 * 2048);
      tv3 = *(const uint4*)(vsrc + keyn + (size_t)96 * 2048);
    }

    // S^T = K x Q^T : two 32x32 key tiles
    f32x16 s0 = fzero16(), s1 = fzero16();
    int swz = l31 & 15;   // (32+l31)&15 == l31&15
#pragma unroll
    for (int kc = 0; kc < 8; ++kc) {
      int slot = (kc * 2 + hi) ^ swz;
      s16x8 a0 = *(const s16x8*)&Kl[l31 * 128 + slot * 8];
      s0 = __builtin_amdgcn_mfma_f32_32x32x16_bf16(a0, qf[kc], s0, 0, 0, 0);
      s16x8 a1 = *(const s16x8*)&Kl[(32 + l31) * 128 + slot * 8];
      s1 = __builtin_amdgcn_mfma_f32_32x32x16_bf16(a1, qf[kc], s1, 0, 0, 0);
    }

    // online softmax, log2 domain (scale folded into Q)
    float mt = s0[0];
#pragma unroll
    for (int r = 1; r < 16; ++r) mt = fmaxf(mt, s0[r]);
#pragma unroll
    for (int r = 0; r < 16; ++r) mt = fmaxf(mt, s1[r]);
    mt = fmaxf(mt, __shfl_xor(mt, 32));
    if (__any(mt > m_run + 8.0f)) {   // defer-max, THR=8 (P <= 256)
      float mnew = fmaxf(m_run, mt);
      float al = exp2f(m_run - mnew);
      m_run = mnew;
      l_run *= al;
#pragma unroll
      for (int df = 0; df < 4; ++df)
#pragma unroll
        for (int r = 0; r < 16; ++r) o[df][r] *= al;
    }
    float ps = 0.f;
    u32 pw[16];   // 4 key-groups x 4 B-frag words
    auto sm_half = [&](const f32x16& sv, u32* pwg) {
#pragma unroll
      for (int g = 0; g < 2; ++g) {
        float p[8];
#pragma unroll
        for (int j = 0; j < 8; ++j) {
          p[j] = exp2f(sv[g * 8 + j] - m_run);
          ps += p[j];
        }
        u32 x0 = cvtpk(p[0], p[1]), y0 = cvtpk(p[4], p[5]);
        u32 x1 = cvtpk(p[2], p[3]), y1 = cvtpk(p[6], p[7]);
        plswap(x0, y0);   // -> (w0, w2)
        plswap(x1, y1);   // -> (w1, w3)
        pwg[g * 4 + 0] = x0;
        pwg[g * 4 + 1] = x1;
        pwg[g * 4 + 2] = y0;
        pwg[g * 4 + 3] = y1;
      }
    };
    sm_half(s0, pw);
    sm_half(s1, pw + 8);
    ps += __shfl_xor(ps, 32);
    l_run += ps;

    // O^T += V^T x P^T
#pragma unroll
    for (int g = 0; g < 4; ++g) {
      u32x4 t;
      t.x = pw[g * 4 + 0];
      t.y = pw[g * 4 + 1];
      t.z = pw[g * 4 + 2];
      t.w = pw[g * 4 + 3];
      s16x8 pf = __builtin_bit_cast(s16x8, t);
#pragma unroll
      for (int df = 0; df < 4; ++df) {
        int idx = (df * 32 + l31) * 68 + (g * 2 + hi) * 8;
        s16x4 va = *(const s16x4*)&Vl[idx];
        s16x4 vb = *(const s16x4*)&Vl[idx + 4];
        s16x8 vf = __builtin_shufflevector(va, vb, 0, 1, 2, 3, 4, 5, 6, 7);
        o[df] = __builtin_amdgcn_mfma_f32_32x32x16_bf16(vf, pf, o[df], 0, 0, 0);
      }
    }
  }

  // epilogue: lane holds O^T column q = l31, rows d = df*32 + (r&3)+8*(r>>2)+4*hi
  float inv = 1.0f / l_run;
  int q = qt * 128 + w * 32 + l31;
  u16* yr = Yg + ((size_t)(b * 2048) + q) * 2048 + h * 128;
#pragma unroll
  for (int df = 0; df < 4; ++df)
#pragma unroll
    for (int q4 = 0; q4 < 4; ++q4) {
      int d0 = df * 32 + q4 * 8 + hi * 4;
      uint2 vv;
      vv.x = cvtpk(o[df][q4 * 4 + 0] * inv, o[df][q4 * 4 + 1] * inv);
      vv.y = cvtpk(o[df][q4 * 4 + 2] * inv, o[df][q4 * 4 + 3] * inv);
      *(uint2*)&yr[d0] = vv;
    }
}

// ---------- launch ----------
extern "C" void kernel_launch(void* const* d_in, const int* in_sizes, int n_in,
                              void* d_out, int out_size, void* d_ws, size_t ws_size,
                              hipStream_t stream) {
  const float* x = (const float*)d_in[0];
  const float* fr = (const float*)d_in[1];
  const float* wqkv = (const float*)d_in[2];
  const float* wproj = (const float*)d_in[3];
  char* ws = (char*)d_ws;
  u16* xbf = (u16*)(ws + 0);                  // 33.5 MB (reused as y after attn)
  u16* wqkvT = (u16*)(ws + 33554432);         // 12.6 MB
  u16* wprojT = (u16*)(ws + 46137344);        // 8.4 MB
  u16* qkv = (u16*)(ws + 54525952);           // 50.3 MB
  u16* Qb = (u16*)(ws + 104857600);           // 33.5 MB
  u16* Kb = (u16*)(ws + 138412032);           // 8.4 MB
  u16* Vtb = (u16*)(ws + 146800640);          // 8.4 MB  (end: 155.2 MB)

  k_convert<<<8192, 256, 0, stream>>>(x, xbf, 8192 * 2048 / 8);
  k_transpose<<<dim3(48, 32), 256, 0, stream>>>(wqkv, wqkvT, 3072, 2048);
  k_transpose<<<dim3(32, 32), 256, 0, stream>>>(wproj, wprojT, 2048, 2048);
  k_gemm_bt<true><<<64 * 24, 256, 0, stream>>>(xbf, wqkvT, qkv, 3072, 2048);
  k_rope_scatter<<<12288, 256, 0, stream>>>(qkv, fr, Qb, Kb, Vtb);
  k_attn<<<1024, 256, 0, stream>>>(Qb, Kb, Vtb, xbf);
  k_gemm_bt<false><<<64 * 16, 256, 0, stream>>>(xbf, wprojT, d_out, 2048, 2048);
}

// Round 3
// 436.555 us; speedup vs baseline: 1.1775x; 1.1775x over previous
//
#include <hip/hip_runtime.h>

using u16 = unsigned short;
using u32 = unsigned int;
typedef float f32x4 __attribute__((ext_vector_type(4)));
typedef float f32x16 __attribute__((ext_vector_type(16)));
typedef short s16x8 __attribute__((ext_vector_type(8)));
typedef short s16x4 __attribute__((ext_vector_type(4)));
typedef unsigned int u32x4 __attribute__((ext_vector_type(4)));

// ---------- helpers ----------
__device__ __forceinline__ u16 f2bf(float x) {
  u32 u = __float_as_uint(x);
  u += 0x7fffu + ((u >> 16) & 1u);   // RTNE
  return (u16)(u >> 16);
}
__device__ __forceinline__ u32 pack2bf(float lo, float hi) {
  return (u32)f2bf(lo) | ((u32)f2bf(hi) << 16);
}
__device__ __forceinline__ float bf2f(u16 v) {
  return __uint_as_float(((u32)v) << 16);
}
__device__ __forceinline__ u32 cvtpk(float lo, float hi) {
  u32 r;
  asm("v_cvt_pk_bf16_f32 %0, %1, %2" : "=v"(r) : "v"(lo), "v"(hi));
  return r;
}
__device__ __forceinline__ void plswap(u32& a, u32& b) {
  // v_permlane32_swap_b32: a.lanes[32:63] <-> b.lanes[0:31]
  asm volatile("v_permlane32_swap_b32 %0, %1" : "+v"(a), "+v"(b));
}
__device__ __forceinline__ void gload16(const u16* g, u16* l) {
  __builtin_amdgcn_global_load_lds(
      (__attribute__((address_space(1))) void*)(u16*)g,
      (__attribute__((address_space(3))) void*)l, 16, 0, 0);
}
__device__ __forceinline__ f32x4 fzero4() {
  f32x4 v = {0.f, 0.f, 0.f, 0.f};
  return v;
}
__device__ __forceinline__ f32x16 fzero16() {
  f32x16 v = {0, 0, 0, 0, 0, 0, 0, 0, 0, 0, 0, 0, 0, 0, 0, 0};
  return v;
}

// ---------- fp32 -> bf16 convert (vectorized) ----------
__global__ __launch_bounds__(256) void k_convert(const float* __restrict__ in,
                                                 u16* __restrict__ out, int n8) {
  int i = blockIdx.x * 256 + threadIdx.x;
  if (i >= n8) return;
  const float4* p = (const float4*)in;
  float4 a = p[2 * i], b = p[2 * i + 1];
  uint4 o;
  o.x = pack2bf(a.x, a.y);
  o.y = pack2bf(a.z, a.w);
  o.z = pack2bf(b.x, b.y);
  o.w = pack2bf(b.z, b.w);
  ((uint4*)out)[i] = o;
}

// ---------- transpose + convert: w [K][N] f32 -> wt [N][K] bf16 ----------
__global__ __launch_bounds__(256) void k_transpose(const float* __restrict__ w,
                                                   u16* __restrict__ wt, int N, int K) {
  __shared__ float tile[64][65];
  int n0 = blockIdx.x * 64, k0 = blockIdx.y * 64;
  int tid = threadIdx.x;
  int rr = tid >> 6, cc = tid & 63;
#pragma unroll
  for (int p = 0; p < 16; ++p)
    tile[p * 4 + rr][cc] = w[(size_t)(k0 + p * 4 + rr) * N + n0 + cc];
  __syncthreads();
#pragma unroll
  for (int p = 0; p < 16; ++p)
    wt[(size_t)(n0 + p * 4 + rr) * K + k0 + cc] = f2bf(tile[cc][p * 4 + rr]);
}

// ---------- GEMM: C[M,N] = A[M,K](bf16) x Bt[N,K](bf16), out bf16 or fp32 ----------
template <bool OBF>
__global__ __launch_bounds__(256) void k_gemm_bt(const u16* __restrict__ A,
                                                 const u16* __restrict__ Bt,
                                                 void* __restrict__ Out, int Nd, int Kd) {
  __shared__ u16 As[2][128 * 32];
  __shared__ u16 Bs[2][128 * 32];
  u32 bid = blockIdx.x, nwg = gridDim.x;
  u32 wgid = (bid & 7) * (nwg >> 3) + (bid >> 3);   // XCD swizzle (nwg % 8 == 0)
  int ntn = Nd >> 7;
  int bm = wgid / ntn, bn = wgid % ntn;
  int tid = threadIdx.x, w = tid >> 6, lane = tid & 63;
  int wm = w >> 1, wn = w & 1;
  int lg = lane >> 4, lq = lane & 15;

  const u16* a0 = A + (size_t)(bm * 128 + w * 32 + (lane >> 2)) * Kd + (lane & 3) * 8;
  const u16* a1 = a0 + (size_t)16 * Kd;
  const u16* b0 = Bt + (size_t)(bn * 128 + w * 32 + (lane >> 2)) * Kd + (lane & 3) * 8;
  const u16* b1 = b0 + (size_t)16 * Kd;

  auto stage = [&](int buf, int k0) {
    gload16(a0 + k0, &As[buf][w * 1024]);
    gload16(a1 + k0, &As[buf][w * 1024 + 512]);
    gload16(b0 + k0, &Bs[buf][w * 1024]);
    gload16(b1 + k0, &Bs[buf][w * 1024 + 512]);
  };

  f32x4 acc[4][4];
#pragma unroll
  for (int m = 0; m < 4; ++m)
#pragma unroll
    for (int n = 0; n < 4; ++n) acc[m][n] = fzero4();

  int nk = Kd >> 5;
  stage(0, 0);
  __syncthreads();
  for (int t = 0; t < nk; ++t) {
    int cur = t & 1;
    if (t + 1 < nk) stage(cur ^ 1, (t + 1) << 5);
    s16x8 af[4], bfr[4];
#pragma unroll
    for (int m = 0; m < 4; ++m)
      af[m] = *(const s16x8*)&As[cur][(wm * 64 + m * 16 + lq) * 32 + lg * 8];
#pragma unroll
    for (int n = 0; n < 4; ++n)
      bfr[n] = *(const s16x8*)&Bs[cur][(wn * 64 + n * 16 + lq) * 32 + lg * 8];
#pragma unroll
    for (int m = 0; m < 4; ++m)
#pragma unroll
      for (int n = 0; n < 4; ++n)
        acc[m][n] = __builtin_amdgcn_mfma_f32_16x16x32_bf16(af[m], bfr[n], acc[m][n], 0, 0, 0);
    __syncthreads();
  }

  int r0 = bm * 128 + wm * 64, c0 = bn * 128 + wn * 64;
  if (OBF) {
    u16* O = (u16*)Out;
#pragma unroll
    for (int m = 0; m < 4; ++m)
#pragma unroll
      for (int n = 0; n < 4; ++n)
#pragma unroll
        for (int r = 0; r < 4; ++r)
          O[(size_t)(r0 + m * 16 + lg * 4 + r) * Nd + c0 + n * 16 + lq] = f2bf(acc[m][n][r]);
  } else {
    float* O = (float*)Out;
#pragma unroll
    for (int m = 0; m < 4; ++m)
#pragma unroll
      for (int n = 0; n < 4; ++n)
#pragma unroll
        for (int r = 0; r < 4; ++r)
          O[(size_t)(r0 + m * 16 + lg * 4 + r) * Nd + c0 + n * 16 + lq] = acc[m][n][r];
  }
}

// ---------- RoPE + scatter to Q / K / V^T (Q pre-scaled by 1/sqrt(HD)*log2e) ----------
__device__ __forceinline__ u32 rope_pair(short a, short b, float c, float s, float sc) {
  float x0 = bf2f((u16)a), x1 = bf2f((u16)b);
  return pack2bf((x0 * c - x1 * s) * sc, (x0 * s + x1 * c) * sc);
}

__global__ __launch_bounds__(256) void k_rope_scatter(const u16* __restrict__ qkv,
                                                      const float* __restrict__ fr,
                                                      u16* __restrict__ Q, u16* __restrict__ K,
                                                      u16* __restrict__ Vt) {
  int idx = blockIdx.x * 256 + threadIdx.x;
  if (idx >= 8192 * 384) return;
  int row = idx / 384, g = idx % 384;
  int b = row >> 11, t = row & 2047;
  int col = g * 8;
  const u16* src = qkv + (size_t)row * 3072 + col;
  if (col < 2560) {
    int isq = col < 2048;
    float sc = isq ? 0.127517432f : 1.0f;   // (1/sqrt(128))*log2(e) folded into Q
    int c2 = isq ? col : col - 2048;
    int h = c2 >> 7, d = c2 & 127;
    u16* dst = isq ? (Q + ((size_t)(b * 16 + h) * 2048 + t) * 128 + d)
                   : (K + ((size_t)(b * 4 + h) * 2048 + t) * 128 + d);
    const float4* fp = (const float4*)(fr + (size_t)t * 128 + d);
    float4 f01 = fp[0], f23 = fp[1];
    s16x8 v = *(const s16x8*)src;
    uint4 o;
    o.x = rope_pair(v[0], v[1], f01.x, f01.y, sc);
    o.y = rope_pair(v[2], v[3], f01.z, f01.w, sc);
    o.z = rope_pair(v[4], v[5], f23.x, f23.y, sc);
    o.w = rope_pair(v[6], v[7], f23.z, f23.w, sc);
    *(uint4*)dst = o;
  } else {
    int c2 = col - 2560;
    int h = c2 >> 7, d = c2 & 127;
    s16x8 v = *(const s16x8*)src;
    u16* base = Vt + ((size_t)(b * 4 + h) * 128 + d) * 2048 + t;
#pragma unroll
    for (int j = 0; j < 8; ++j) base[(size_t)j * 2048] = (u16)v[j];
  }
}

// ---------- flash attention, 32x32 MFMA, in-register P, 2-phase double-buffer ----------
// Q [64bh][2048][128] (pre-scaled), K [16bkv][2048][128], Vt [16bkv][128][2048]
// -> Y [B*T][2048] bf16.  4 waves x 32q = 128 q-rows per block, KV tile 64.
__global__ __launch_bounds__(256, 2) void k_attn(const u16* __restrict__ Qg,
                                                 const u16* __restrict__ Kg,
                                                 const u16* __restrict__ Vg,
                                                 u16* __restrict__ Yg) {
  __shared__ u16 Kl[2][64 * 128];   // 2 x 16 KB, 4-bit XOR swizzle on 16B slots
  __shared__ u16 Vl[2][128 * 68];   // 2 x 17 KB, +4 u16 pad (34-bank row stride)
  u32 bid = blockIdx.x;
  u32 wgid = (bid & 7) * 128 + (bid >> 3);   // XCD swizzle (1024 wgs)
  int qt = wgid & 15, bh = wgid >> 4;
  int b = bh >> 4, h = bh & 15, kvh = h >> 2;
  int tid = threadIdx.x, w = tid >> 6, lane = tid & 63;
  int l31 = lane & 31, hi = lane >> 5;
  const u16* Qb = Qg + ((size_t)bh * 2048 + qt * 128 + w * 32 + l31) * 128;
  const u16* Kb = Kg + (size_t)(b * 4 + kvh) * 2048 * 128;
  const u16* Vb = Vg + (size_t)(b * 4 + kvh) * 128 * 2048;

  // Q fragments: B-operand of 32x32x16, col=q=l31, k = hi*8+j within kc*16
  s16x8 qf[8];
#pragma unroll
  for (int kc = 0; kc < 8; ++kc)
    qf[kc] = *(const s16x8*)(Qb + kc * 16 + hi * 8);

  f32x16 o[4];
#pragma unroll
  for (int i = 0; i < 4; ++i) o[i] = fzero16();
  float m_run = -3.0e38f, l_run = 0.f;

  // staging geometry
  int krow4 = lane >> 4;           // row-within-4 for K gload
  int kc_ = lane & 15;             // 16B slot within K row
  int vd = tid >> 3;               // V d-row (0..31), +32*i
  int vc = tid & 7;                // 16B slot within V row (8 per 64-key row)
  const u16* vsrc = Vb + (size_t)vd * 2048 + vc * 8;

  auto stageK = [&](int buf, int key0) {
#pragma unroll
    for (int i = 0; i < 4; ++i) {
      int key = w * 16 + i * 4 + krow4;
      gload16(Kb + (size_t)(key0 + key) * 128 + ((kc_ ^ (key & 15)) * 8),
              &Kl[buf][(w * 4 + i) * 512]);
    }
  };
  auto writeV = [&](int buf, const uint4& t0, const uint4& t1, const uint4& t2,
                    const uint4& t3) {
    u16* p = &Vl[buf][vd * 68 + vc * 8];
    *(uint2*)p = make_uint2(t0.x, t0.y);
    *(uint2*)(p + 4) = make_uint2(t0.z, t0.w);
    p += 32 * 68;
    *(uint2*)p = make_uint2(t1.x, t1.y);
    *(uint2*)(p + 4) = make_uint2(t1.z, t1.w);
    p += 32 * 68;
    *(uint2*)p = make_uint2(t2.x, t2.y);
    *(uint2*)(p + 4) = make_uint2(t2.z, t2.w);
    p += 32 * 68;
    *(uint2*)p = make_uint2(t3.x, t3.y);
    *(uint2*)(p + 4) = make_uint2(t3.z, t3.w);
  };

  // ---- prologue: tile 0 into buffer 0 ----
  {
    uint4 t0 = *(const uint4*)(vsrc);
    uint4 t1 = *(const uint4*)(vsrc + (size_t)32 * 2048);
    uint4 t2 = *(const uint4*)(vsrc + (size_t)64 * 2048);
    uint4 t3 = *(const uint4*)(vsrc + (size_t)96 * 2048);
    stageK(0, 0);
    writeV(0, t0, t1, t2, t3);
  }
  __syncthreads();

  for (int kt = 0; kt < 32; ++kt) {
    int cur = kt & 1;
    // issue next-tile V loads FIRST (oldest vmem -> counted wait skips K gloads)
    uint4 tv0, tv1, tv2, tv3;
    if (kt < 31) {
      const u16* vs = vsrc + (kt + 1) * 64;
      tv0 = *(const uint4*)(vs);
      tv1 = *(const uint4*)(vs + (size_t)32 * 2048);
      tv2 = *(const uint4*)(vs + (size_t)64 * 2048);
      tv3 = *(const uint4*)(vs + (size_t)96 * 2048);
      stageK(cur ^ 1, (kt + 1) * 64);
    }

    // S^T = K x Q^T : two 32x32 key tiles from Kl[cur]
    f32x16 s0 = fzero16(), s1 = fzero16();
    int swz = l31 & 15;   // (32+l31)&15 == l31&15
#pragma unroll
    for (int kc = 0; kc < 8; ++kc) {
      int slot = (kc * 2 + hi) ^ swz;
      s16x8 a0 = *(const s16x8*)&Kl[cur][l31 * 128 + slot * 8];
      s0 = __builtin_amdgcn_mfma_f32_32x32x16_bf16(a0, qf[kc], s0, 0, 0, 0);
      s16x8 a1 = *(const s16x8*)&Kl[cur][(32 + l31) * 128 + slot * 8];
      s1 = __builtin_amdgcn_mfma_f32_32x32x16_bf16(a1, qf[kc], s1, 0, 0, 0);
    }

    // online softmax, log2 domain (scale folded into Q)
    float mt = s0[0];
#pragma unroll
    for (int r = 1; r < 16; ++r) mt = fmaxf(mt, s0[r]);
#pragma unroll
    for (int r = 0; r < 16; ++r) mt = fmaxf(mt, s1[r]);
    mt = fmaxf(mt, __shfl_xor(mt, 32));
    if (__any(mt > m_run + 8.0f)) {   // defer-max, THR=8 (P <= 256)
      float mnew = fmaxf(m_run, mt);
      float al = exp2f(m_run - mnew);
      m_run = mnew;
      l_run *= al;
#pragma unroll
      for (int df = 0; df < 4; ++df)
#pragma unroll
        for (int r = 0; r < 16; ++r) o[df][r] *= al;
    }
    float ps = 0.f;
    u32 pw[16];   // 4 key-groups x 4 B-frag words
    auto sm_half = [&](const f32x16& sv, u32* pwg) {
#pragma unroll
      for (int g = 0; g < 2; ++g) {
        float p[8];
#pragma unroll
        for (int j = 0; j < 8; ++j) {
          p[j] = exp2f(sv[g * 8 + j] - m_run);
          ps += p[j];
        }
        u32 x0 = cvtpk(p[0], p[1]), y0 = cvtpk(p[4], p[5]);
        u32 x1 = cvtpk(p[2], p[3]), y1 = cvtpk(p[6], p[7]);
        plswap(x0, y0);   // -> (w0, w2)
        plswap(x1, y1);   // -> (w1, w3)
        pwg[g * 4 + 0] = x0;
        pwg[g * 4 + 1] = x1;
        pwg[g * 4 + 2] = y0;
        pwg[g * 4 + 3] = y1;
      }
    };
    sm_half(s0, pw);
    sm_half(s1, pw + 8);
    ps += __shfl_xor(ps, 32);
    l_run += ps;

    // stash next V tile into LDS buf^1 (vmcnt wait on tv covered by QK+softmax)
    if (kt < 31) writeV(cur ^ 1, tv0, tv1, tv2, tv3);

    // O^T += V^T x P^T  from Vl[cur]
#pragma unroll
    for (int g = 0; g < 4; ++g) {
      u32x4 t;
      t.x = pw[g * 4 + 0];
      t.y = pw[g * 4 + 1];
      t.z = pw[g * 4 + 2];
      t.w = pw[g * 4 + 3];
      s16x8 pf = __builtin_bit_cast(s16x8, t);
#pragma unroll
      for (int df = 0; df < 4; ++df) {
        int idx = (df * 32 + l31) * 68 + (g * 2 + hi) * 8;
        s16x4 va = *(const s16x4*)&Vl[cur][idx];
        s16x4 vb = *(const s16x4*)&Vl[cur][idx + 4];
        s16x8 vf = __builtin_shufflevector(va, vb, 0, 1, 2, 3, 4, 5, 6, 7);
        o[df] = __builtin_amdgcn_mfma_f32_32x32x16_bf16(vf, pf, o[df], 0, 0, 0);
      }
    }
    __syncthreads();   // releases buf^1 for next iter; K(t+1) latency already covered
  }

  // epilogue: lane holds O^T column q = l31, rows d = df*32 + (r&3)+8*(r>>2)+4*hi
  float inv = 1.0f / l_run;
  int q = qt * 128 + w * 32 + l31;
  u16* yr = Yg + ((size_t)(b * 2048) + q) * 2048 + h * 128;
#pragma unroll
  for (int df = 0; df < 4; ++df)
#pragma unroll
    for (int q4 = 0; q4 < 4; ++q4) {
      int d0 = df * 32 + q4 * 8 + hi * 4;
      uint2 vv;
      vv.x = cvtpk(o[df][q4 * 4 + 0] * inv, o[df][q4 * 4 + 1] * inv);
      vv.y = cvtpk(o[df][q4 * 4 + 2] * inv, o[df][q4 * 4 + 3] * inv);
      *(uint2*)&yr[d0] = vv;
    }
}

// ---------- launch ----------
extern "C" void kernel_launch(void* const* d_in, const int* in_sizes, int n_in,
                              void* d_out, int out_size, void* d_ws, size_t ws_size,
                              hipStream_t stream) {
  const float* x = (const float*)d_in[0];
  const float* fr = (const float*)d_in[1];
  const float* wqkv = (const float*)d_in[2];
  const float* wproj = (const float*)d_in[3];
  char* ws = (char*)d_ws;
  u16* xbf = (u16*)(ws + 0);                  // 33.5 MB (reused as y after attn)
  u16* wqkvT = (u16*)(ws + 33554432);         // 12.6 MB
  u16* wprojT = (u16*)(ws + 46137344);        // 8.4 MB
  u16* qkv = (u16*)(ws + 54525952);           // 50.3 MB
  u16* Qb = (u16*)(ws + 104857600);           // 33.5 MB
  u16* Kb = (u16*)(ws + 138412032);           // 8.4 MB
  u16* Vtb = (u16*)(ws + 146800640);          // 8.4 MB  (end: 155.2 MB)

  k_convert<<<8192, 256, 0, stream>>>(x, xbf, 8192 * 2048 / 8);
  k_transpose<<<dim3(48, 32), 256, 0, stream>>>(wqkv, wqkvT, 3072, 2048);
  k_transpose<<<dim3(32, 32), 256, 0, stream>>>(wproj, wprojT, 2048, 2048);
  k_gemm_bt<true><<<64 * 24, 256, 0, stream>>>(xbf, wqkvT, qkv, 3072, 2048);
  k_rope_scatter<<<12288, 256, 0, stream>>>(qkv, fr, Qb, Kb, Vtb);
  k_attn<<<1024, 256, 0, stream>>>(Qb, Kb, Vtb, xbf);
  k_gemm_bt<false><<<64 * 16, 256, 0, stream>>>(xbf, wprojT, d_out, 2048, 2048);
}